// Round 2
// baseline (156.669 us; speedup 1.0000x reference)
//
#include <hip/hip_runtime.h>
#include <stdint.h>
#include <math.h>

// MulHeadAttn on MI355X. B=2, C=1024, E=1024, head_dim(H)=16, n_heads(HD)=64.
// cast(fp32->bf16, Wq pre-scaled 0.25*log2e) -> fused QKV bf16-MFMA GEMM
// (R10: 128x128 tile, 4x4 acc/wave, global_load_lds dbuf — m97 replica) ->
// MFMA flash attention (no-max softmax in exp2 domain; transposed QK;
// v_perm P-pack) -> bf16-MFMA O-projection (64x128 tile kernel).

typedef __bf16   bf16x8 __attribute__((ext_vector_type(8)));
typedef float    f32x4  __attribute__((ext_vector_type(4)));

__device__ __forceinline__ unsigned short f2bf(float f) {
    unsigned int u = __float_as_uint(f);
    u += 0x7FFFu + ((u >> 16) & 1u);         // round-to-nearest-even
    return (unsigned short)(u >> 16);
}

// pack two fp32 -> two bf16 (round-nearest-ties-away): 2 adds + 1 v_perm
__device__ __forceinline__ unsigned int pkbf(float lo, float hi) {
    const unsigned int ulo = __float_as_uint(lo) + 0x8000u;
    const unsigned int uhi = __float_as_uint(hi) + 0x8000u;
    return __builtin_amdgcn_perm(uhi, ulo, 0x07060302u);  // [uhi.hi16 | ulo.hi16]
}

// async global->LDS, 16 bytes per lane (dest = wave-uniform base + lane*16)
__device__ __forceinline__ void gl16(const unsigned short* g, unsigned short* l) {
    __builtin_amdgcn_global_load_lds(
        (const __attribute__((address_space(1))) unsigned int*)g,
        (__attribute__((address_space(3))) unsigned int*)l, 16, 0, 0);
}

// ---------------------------------------------------------------- cast ----
// z=0,1: halves of x; z=2: Wq scaled 0.25*log2(e) (softmax scale folded into
// the exp2 domain); z=3..5: Wk, Wv, Wo.
__global__ __launch_bounds__(256) void cast_to_bf16(
    const float* __restrict__ x,
    const float* __restrict__ w0, const float* __restrict__ w1,
    const float* __restrict__ w2, const float* __restrict__ w3,
    unsigned short* __restrict__ xb,
    unsigned short* __restrict__ b0, unsigned short* __restrict__ b1,
    unsigned short* __restrict__ b2, unsigned short* __restrict__ b3)
{
    const int z = blockIdx.y;
    const float* src;
    unsigned short* dst;
    size_t off = 0;
    float sc = 1.f;
    if (z < 2)       { src = x;  dst = xb; off = (size_t)z << 20; }
    else if (z == 2) { src = w0; dst = b0; sc = 0.36067376022224085f; } // 0.25*log2e
    else if (z == 3) { src = w1; dst = b1; }
    else if (z == 4) { src = w2; dst = b2; }
    else             { src = w3; dst = b3; }
    const size_t i = off + ((size_t)blockIdx.x * 256 + threadIdx.x) * 4;
    const float4 v = *(const float4*)(src + i);
    *(ushort4*)(dst + i) = make_ushort4(f2bf(v.x * sc), f2bf(v.y * sc),
                                        f2bf(v.z * sc), f2bf(v.w * sc));
}

// ------------------------------------------------------- GEMM 128x128 ----
// R10: m97 replica for the QKV GEMM. 128x128 tile, BK=32, 4 waves each
// computing a 64x64 sub-tile via acc[4][4] of 16x16x32 MFMA. Staging:
// global_load_lds width-16, double-buffered, one barrier per K-step.
// 8 ds_read_b128 feed 16 MFMA per wave per K-step (0.5 DS:MFMA vs 0.75
// in the 64x128 kernel) — halves LDS cycles per FLOP.
__global__ __launch_bounds__(256) void gemm128_bt_mfma(
    const unsigned short* __restrict__ A,
    const unsigned short* __restrict__ B0, const unsigned short* __restrict__ B1,
    const unsigned short* __restrict__ B2,
    unsigned short* __restrict__ C0, unsigned short* __restrict__ C1,
    unsigned short* __restrict__ C2,
    int M, int N, int K)
{
    const unsigned short* Bm = (blockIdx.z == 0) ? B0 : (blockIdx.z == 1) ? B1 : B2;
    unsigned short* Cm       = (blockIdx.z == 0) ? C0 : (blockIdx.z == 1) ? C1 : C2;

    __shared__ __align__(16) unsigned short As[2][128 * 32];  // 16 KB
    __shared__ __align__(16) unsigned short Bs[2][128 * 32];  // 16 KB

    const int t    = threadIdx.x;
    const int lane = t & 63;
    const int w    = t >> 6;
    const int m0   = blockIdx.y * 128;
    const int n0   = blockIdx.x * 128;
    const int wm   = (w & 1) * 64;
    const int wn   = (w >> 1) * 64;

    // staging: thread t covers row t>>2 (and +64), cols (t&3)*8 .. +8
    const int r0 = t >> 2;
    const int c0 = (t & 3) * 8;
    const unsigned short* Apa = A  + (size_t)(m0 + r0) * K + c0;
    const unsigned short* Apb = Apa + (size_t)64 * K;
    const unsigned short* Bpa = Bm + (size_t)(n0 + r0) * K + c0;
    const unsigned short* Bpb = Bpa + (size_t)64 * K;
    // wave-uniform LDS bases (gl16 adds lane*16B): wave w stages 1 KB chunks
    unsigned short* lA0 = &As[0][w * 512];
    unsigned short* lA1 = &As[0][2048 + w * 512];
    unsigned short* lB0 = &Bs[0][w * 512];
    unsigned short* lB1 = &Bs[0][2048 + w * 512];
    const int bufStr = 128 * 32;   // u16 elements per buffer

    f32x4 acc[4][4];
#pragma unroll
    for (int i = 0; i < 4; ++i)
#pragma unroll
        for (int j = 0; j < 4; ++j) acc[i][j] = (f32x4){0.f, 0.f, 0.f, 0.f};

    const int fm = lane & 15;
    const int kg = lane >> 4;

    // prologue: stage tile 0 into buffer 0
    gl16(Apa, lA0);
    gl16(Apb, lA1);
    gl16(Bpa, lB0);
    gl16(Bpb, lB1);

    int cur = 0;
    for (int k0 = 0; k0 < K; k0 += 32) {
        // drains vmcnt(0)+lgkmcnt(0): buf[cur] staged, all prior reads done
        __syncthreads();

        if (k0 + 32 < K) {   // stage next tile into buf[cur^1]
            const int nb = (cur ^ 1);
            gl16(Apa + k0 + 32, lA0 + nb * bufStr);
            gl16(Apb + k0 + 32, lA1 + nb * bufStr);
            gl16(Bpa + k0 + 32, lB0 + nb * bufStr);
            gl16(Bpb + k0 + 32, lB1 + nb * bufStr);
        }

        const unsigned short* Ab = &As[cur][0];
        const unsigned short* Bb = &Bs[cur][0];
        bf16x8 af[4], bfr[4];
#pragma unroll
        for (int im = 0; im < 4; ++im)
            af[im] = *(const bf16x8*)&Ab[(wm + im * 16 + fm) * 32 + kg * 8];
#pragma unroll
        for (int in = 0; in < 4; ++in)
            bfr[in] = *(const bf16x8*)&Bb[(wn + in * 16 + fm) * 32 + kg * 8];
#pragma unroll
        for (int im = 0; im < 4; ++im)
#pragma unroll
            for (int in = 0; in < 4; ++in)
                acc[im][in] = __builtin_amdgcn_mfma_f32_16x16x32_bf16(
                    af[im], bfr[in], acc[im][in], 0, 0, 0);

        cur ^= 1;
    }

#pragma unroll
    for (int im = 0; im < 4; ++im) {
#pragma unroll
        for (int in = 0; in < 4; ++in) {
            const int row = m0 + wm + im * 16 + kg * 4;
            const int col = n0 + wn + in * 16 + fm;
#pragma unroll
            for (int r = 0; r < 4; ++r)
                Cm[(size_t)(row + r) * N + col] = f2bf(acc[im][in][r]);
        }
    }
}

// -------------------------------------------------------- GEMM 64x128 ----
// (unchanged R9 kernel — used for the O-projection where 128x128 tiling
// would leave half the CUs idle: 256 blocks vs 128.)
__global__ __launch_bounds__(256) void gemm_bt_mfma(
    const unsigned short* __restrict__ A,
    const unsigned short* __restrict__ B0, const unsigned short* __restrict__ B1,
    const unsigned short* __restrict__ B2,
    void* __restrict__ C0, void* __restrict__ C1, void* __restrict__ C2,
    int M, int N, int K, int bf16out)
{
    const unsigned short* Bm = (blockIdx.z == 0) ? B0 : (blockIdx.z == 1) ? B1 : B2;
    void* Cm                 = (blockIdx.z == 0) ? C0 : (blockIdx.z == 1) ? C1 : C2;

    __shared__ __align__(16) unsigned short As[2][64 * 32];   //  8 KB
    __shared__ __align__(16) unsigned short Bs[2][128 * 32];  // 16 KB

    const int t    = threadIdx.x;
    const int lane = t & 63;
    const int w    = t >> 6;
    const int m0   = blockIdx.y * 64;
    const int n0   = blockIdx.x * 128;
    const int wm   = (w & 1) * 32;
    const int wn   = (w >> 1) * 64;

    const int r0 = t >> 2;
    const int c0 = (t & 3) * 8;
    const unsigned short* Apa = A  + (size_t)(m0 + r0) * K + c0;
    const unsigned short* Bpa = Bm + (size_t)(n0 + r0) * K + c0;
    const unsigned short* Bpb = Bm + (size_t)(n0 + r0 + 64) * K + c0;
    unsigned short* ldsA  = &As[0][w * 512];
    unsigned short* ldsB0 = &Bs[0][w * 512];
    unsigned short* ldsB1 = &Bs[0][2048 + w * 512];
    const int bufStrA = 64 * 32;
    const int bufStrB = 128 * 32;

    f32x4 acc[2][4];
#pragma unroll
    for (int i = 0; i < 2; ++i)
#pragma unroll
        for (int j = 0; j < 4; ++j) acc[i][j] = (f32x4){0.f, 0.f, 0.f, 0.f};

    const int fm = lane & 15;
    const int kg = lane >> 4;

    gl16(Apa, ldsA);
    gl16(Bpa, ldsB0);
    gl16(Bpb, ldsB1);

    int cur = 0;
    for (int k0 = 0; k0 < K; k0 += 32) {
        __syncthreads();

        if (k0 + 32 < K) {
            const int nb = (cur ^ 1);
            gl16(Apa + k0 + 32, ldsA  + nb * bufStrA);
            gl16(Bpa + k0 + 32, ldsB0 + nb * bufStrB);
            gl16(Bpb + k0 + 32, ldsB1 + nb * bufStrB);
        }

        const unsigned short* Ab = &As[cur][0];
        const unsigned short* Bb = &Bs[cur][0];
        bf16x8 af[2], bfr[4];
#pragma unroll
        for (int im = 0; im < 2; ++im)
            af[im] = *(const bf16x8*)&Ab[(wm + im * 16 + fm) * 32 + kg * 8];
#pragma unroll
        for (int in = 0; in < 4; ++in)
            bfr[in] = *(const bf16x8*)&Bb[(wn + in * 16 + fm) * 32 + kg * 8];
#pragma unroll
        for (int im = 0; im < 2; ++im)
#pragma unroll
            for (int in = 0; in < 4; ++in)
                acc[im][in] = __builtin_amdgcn_mfma_f32_16x16x32_bf16(
                    af[im], bfr[in], acc[im][in], 0, 0, 0);

        cur ^= 1;
    }

#pragma unroll
    for (int im = 0; im < 2; ++im) {
#pragma unroll
        for (int in = 0; in < 4; ++in) {
            const int row = m0 + wm + im * 16 + kg * 4;
            const int col = n0 + wn + in * 16 + fm;
            if (bf16out) {
                unsigned short* cp = (unsigned short*)Cm;
#pragma unroll
                for (int r = 0; r < 4; ++r)
                    cp[(size_t)(row + r) * N + col] = f2bf(acc[im][in][r]);
            } else {
                float* cp = (float*)Cm;
#pragma unroll
                for (int r = 0; r < 4; ++r)
                    cp[(size_t)(row + r) * N + col] = acc[im][in][r];
            }
        }
    }
}

// ----------------------------------------------------------- attention ----
// grid (8, 128): one block = one (b,hd) x 128 q-rows -> 1024 blocks = 4/CU.
// 4 waves; wave wq owns q-rows [wq*32, wq*32+32). Per 64-key tile:
//   - stage K [64][KSTR2] bf16 (d=16 real + 16 zero-pad) and V transposed
//   - QK transposed: s = mfma(K_frag, Q_frag); lane = (key quad, q=fm)
//   - p = exp2(s)  (scale*log2e folded into Wq; softmax base-invariant)
//   - pack pairs via +0x8000 + v_perm (RNTA) -> ds_write_b64 into Ps[q][key]
//   - PV: P rows as A-frags (wave-local), V^T as B-frags
#define KSTR2 40
#define VSTR2 72
#define PSTR  80

__global__ __launch_bounds__(256) void attn_mfma(
    const unsigned short* __restrict__ Qb, const unsigned short* __restrict__ Kb,
    const unsigned short* __restrict__ Vb, unsigned short* __restrict__ Ob)
{
    __shared__ __align__(16) unsigned short Ks[64 * KSTR2];    //  5.0 KB
    __shared__ __align__(16) unsigned short VsT[16 * VSTR2];   //  2.3 KB
    __shared__ __align__(16) unsigned short Ps[128 * PSTR];    // 20.0 KB
    __shared__ __align__(16) float Lsh[128];                   //  0.5 KB

    const int t    = threadIdx.x;
    const int lane = t & 63;
    const int wq   = t >> 6;
    const int fm   = lane & 15;
    const int kg   = lane >> 4;
    const int bh   = blockIdx.y;
    const size_t base = ((size_t)(bh >> 6) * 1024) * 1024 + (size_t)(bh & 63) * 16;
    const int q0 = blockIdx.x * 128;

    // zero the K k-pad once (real cols rewritten per tile, pad never)
    if (t < 128) {
        const int row = t >> 1, seg = t & 1;
        *(uint4*)&Ks[row * KSTR2 + 16 + seg * 8] = make_uint4(0, 0, 0, 0);
    }

    // Q fragments (B-operand): row q0+wq*32+m*16+fm, k=kg*8 (zero kg>=2)
    union { uint4 u; bf16x8 h; } zz; zz.u = make_uint4(0, 0, 0, 0);
    bf16x8 aq[2];
#pragma unroll
    for (int m = 0; m < 2; ++m) {
        if (kg < 2)
            aq[m] = *(const bf16x8*)(Qb + base +
                     (size_t)(q0 + wq * 32 + m * 16 + fm) * 1024 + kg * 8);
        else
            aq[m] = zz.h;
    }

    f32x4 oacc[2];
    float lp[2];
#pragma unroll
    for (int m = 0; m < 2; ++m) {
        oacc[m] = (f32x4){0.f, 0.f, 0.f, 0.f};
        lp[m] = 0.f;
    }

    for (int kt = 0; kt < 1024; kt += 64) {
        __syncthreads();
        if (t < 128) {           // K tile: 64 rows x 16 real bf16
            const int row = t >> 1, seg = t & 1;
            *(uint4*)&Ks[row * KSTR2 + seg * 8] =
                *(const uint4*)(Kb + base + (size_t)(kt + row) * 1024 + seg * 8);
        } else {                 // V tile, transposed: VsT[d][key]
            const int idx = t - 128;
            const int key = idx >> 1, half = idx & 1;
            uint4 v = *(const uint4*)(Vb + base + (size_t)(kt + key) * 1024 + half * 8);
            const unsigned short* pv = (const unsigned short*)&v;
#pragma unroll
            for (int d = 0; d < 8; ++d)
                VsT[(half * 8 + d) * VSTR2 + key] = pv[d];
        }
        __syncthreads();

        // K fragments (A-operand): row kn*16+fm, k=kg*8
        bf16x8 bk[4];
#pragma unroll
        for (int kn = 0; kn < 4; ++kn)
            bk[kn] = *(const bf16x8*)&Ks[(kn * 16 + fm) * KSTR2 + kg * 8];

        // ---- transposed QK + exp2 + packed b64 P-store
#pragma unroll
        for (int kn = 0; kn < 4; ++kn) {
            f32x4 sm[2];
#pragma unroll
            for (int m = 0; m < 2; ++m)
                sm[m] = __builtin_amdgcn_mfma_f32_16x16x32_bf16(
                    bk[kn], aq[m], (f32x4){0.f, 0.f, 0.f, 0.f}, 0, 0, 0);
#pragma unroll
            for (int m = 0; m < 2; ++m) {
                const float p0 = __builtin_amdgcn_exp2f(sm[m][0]);
                const float p1 = __builtin_amdgcn_exp2f(sm[m][1]);
                const float p2 = __builtin_amdgcn_exp2f(sm[m][2]);
                const float p3 = __builtin_amdgcn_exp2f(sm[m][3]);
                lp[m] += (p0 + p1) + (p2 + p3);
                *(uint2*)&Ps[(wq * 32 + m * 16 + fm) * PSTR + kn * 16 + kg * 4] =
                    make_uint2(pkbf(p0, p1), pkbf(p2, p3));
            }
        }

        // ---- PV: O[32q x 16d] += P[32q x 64k] * V[64k x 16d]  (wave-local)
        bf16x8 bv0 = *(const bf16x8*)&VsT[fm * VSTR2 + kg * 8];
        bf16x8 bv1 = *(const bf16x8*)&VsT[fm * VSTR2 + 32 + kg * 8];
#pragma unroll
        for (int m = 0; m < 2; ++m) {
            const int prow = wq * 32 + m * 16 + fm;
            bf16x8 ap0 = *(const bf16x8*)&Ps[prow * PSTR + kg * 8];
            bf16x8 ap1 = *(const bf16x8*)&Ps[prow * PSTR + 32 + kg * 8];
            oacc[m] = __builtin_amdgcn_mfma_f32_16x16x32_bf16(ap0, bv0, oacc[m], 0, 0, 0);
            oacc[m] = __builtin_amdgcn_mfma_f32_16x16x32_bf16(ap1, bv1, oacc[m], 0, 0, 0);
        }
    }

    // l: sum the 4 kg-group partials, transpose via LDS (wave-local)
#pragma unroll
    for (int m = 0; m < 2; ++m) {
        float v = lp[m];
        v += __shfl_xor(v, 16, 64);
        v += __shfl_xor(v, 32, 64);
        if (kg == 0) Lsh[wq * 32 + m * 16 + fm] = v;
    }

    // epilogue: C-layout rows = q (kg*4+r), cols = d (fm)
#pragma unroll
    for (int m = 0; m < 2; ++m) {
        const float4 lr = *(const float4*)&Lsh[wq * 32 + m * 16 + kg * 4];
        const int qrow = q0 + wq * 32 + m * 16 + kg * 4;
        Ob[base + (size_t)(qrow + 0) * 1024 + fm] = f2bf(oacc[m][0] / lr.x);
        Ob[base + (size_t)(qrow + 1) * 1024 + fm] = f2bf(oacc[m][1] / lr.y);
        Ob[base + (size_t)(qrow + 2) * 1024 + fm] = f2bf(oacc[m][2] / lr.z);
        Ob[base + (size_t)(qrow + 3) * 1024 + fm] = f2bf(oacc[m][3] / lr.w);
    }
}

// -------------------------------------------------------------- launch ----
extern "C" void kernel_launch(void* const* d_in, const int* in_sizes, int n_in,
                              void* d_out, int out_size, void* d_ws, size_t ws_size,
                              hipStream_t stream) {
    const float* x  = (const float*)d_in[0];
    const float* Wq = (const float*)d_in[1];
    const float* Wk = (const float*)d_in[2];
    const float* Wv = (const float*)d_in[3];
    const float* Wo = (const float*)d_in[4];
    float* out = (float*)d_out;

    const int M = 2048, N = 1024, Kd = 1024;
    const size_t MEG = 1048576;
    unsigned short* ws = (unsigned short*)d_ws;   // 28 MB high-water
    unsigned short* xb  = ws;
    unsigned short* Wqb = ws + 2 * MEG;
    unsigned short* Wkb = ws + 3 * MEG;
    unsigned short* Wvb = ws + 4 * MEG;
    unsigned short* Wob = ws + 5 * MEG;
    unsigned short* Qb  = ws + 6 * MEG;
    unsigned short* Kb  = ws + 8 * MEG;
    unsigned short* Vb  = ws + 10 * MEG;
    unsigned short* Ob  = ws + 12 * MEG;

    dim3 gc(1024, 6, 1);
    cast_to_bf16<<<gc, 256, 0, stream>>>(x, Wq, Wk, Wv, Wo, xb, Wqb, Wkb, Wvb, Wob);

    dim3 g1(N / 128, M / 128, 3);
    gemm128_bt_mfma<<<g1, 256, 0, stream>>>(xb, Wqb, Wkb, Wvb, Qb, Kb, Vb, M, N, Kd);

    dim3 g2(8, 128, 1);
    attn_mfma<<<g2, 256, 0, stream>>>(Qb, Kb, Vb, Ob);

    dim3 g3(N / 128, M / 64, 1);
    gemm_bt_mfma<<<g3, 256, 0, stream>>>(Ob, Wob, Wob, Wob, out, out, out, M, N, Kd, 0);
}

// Round 3
// 153.306 us; speedup vs baseline: 1.0219x; 1.0219x over previous
//
#include <hip/hip_runtime.h>
#include <stdint.h>
#include <math.h>

// MulHeadAttn on MI355X. B=2, C=1024, E=1024, head_dim(H)=16, n_heads(HD)=64.
// cast(fp32->bf16, Wq pre-scaled 0.25*log2e) -> fused QKV bf16-MFMA GEMM
// (128x128 tile, global_load_lds dbuf) -> MFMA flash attention
// (R11: keys-split waves — each wave owns 32 keys x all 128 q; KV tile 128;
//  LDS reads -45%; cvt_pk P-pack; cross-wave O/l reduction in overlaid LDS)
// -> bf16-MFMA O-projection (64x128 tile kernel).

typedef __bf16   bf16x8 __attribute__((ext_vector_type(8)));
typedef float    f32x4  __attribute__((ext_vector_type(4)));

__device__ __forceinline__ unsigned short f2bf(float f) {
    unsigned int u = __float_as_uint(f);
    u += 0x7FFFu + ((u >> 16) & 1u);         // round-to-nearest-even
    return (unsigned short)(u >> 16);
}

// pack two fp32 -> u32 of two bf16 (RNE), single VALU op
__device__ __forceinline__ unsigned int cvtpk(float lo, float hi) {
    unsigned int r;
    asm("v_cvt_pk_bf16_f32 %0, %1, %2" : "=v"(r) : "v"(lo), "v"(hi));
    return r;
}

// async global->LDS, 16 bytes per lane (dest = wave-uniform base + lane*16)
__device__ __forceinline__ void gl16(const unsigned short* g, unsigned short* l) {
    __builtin_amdgcn_global_load_lds(
        (const __attribute__((address_space(1))) unsigned int*)g,
        (__attribute__((address_space(3))) unsigned int*)l, 16, 0, 0);
}

// ---------------------------------------------------------------- cast ----
// z=0,1: halves of x; z=2: Wq scaled 0.25*log2(e) (softmax scale folded into
// the exp2 domain); z=3..5: Wk, Wv, Wo.
__global__ __launch_bounds__(256) void cast_to_bf16(
    const float* __restrict__ x,
    const float* __restrict__ w0, const float* __restrict__ w1,
    const float* __restrict__ w2, const float* __restrict__ w3,
    unsigned short* __restrict__ xb,
    unsigned short* __restrict__ b0, unsigned short* __restrict__ b1,
    unsigned short* __restrict__ b2, unsigned short* __restrict__ b3)
{
    const int z = blockIdx.y;
    const float* src;
    unsigned short* dst;
    size_t off = 0;
    float sc = 1.f;
    if (z < 2)       { src = x;  dst = xb; off = (size_t)z << 20; }
    else if (z == 2) { src = w0; dst = b0; sc = 0.36067376022224085f; } // 0.25*log2e
    else if (z == 3) { src = w1; dst = b1; }
    else if (z == 4) { src = w2; dst = b2; }
    else             { src = w3; dst = b3; }
    const size_t i = off + ((size_t)blockIdx.x * 256 + threadIdx.x) * 4;
    const float4 v = *(const float4*)(src + i);
    *(ushort4*)(dst + i) = make_ushort4(f2bf(v.x * sc), f2bf(v.y * sc),
                                        f2bf(v.z * sc), f2bf(v.w * sc));
}

// ------------------------------------------------------- GEMM 128x128 ----
// QKV GEMM: 128x128 tile, BK=32, 4 waves each computing a 64x64 sub-tile
// via acc[4][4] of 16x16x32 MFMA. global_load_lds width-16, double-buffered.
__global__ __launch_bounds__(256) void gemm128_bt_mfma(
    const unsigned short* __restrict__ A,
    const unsigned short* __restrict__ B0, const unsigned short* __restrict__ B1,
    const unsigned short* __restrict__ B2,
    unsigned short* __restrict__ C0, unsigned short* __restrict__ C1,
    unsigned short* __restrict__ C2,
    int M, int N, int K)
{
    const unsigned short* Bm = (blockIdx.z == 0) ? B0 : (blockIdx.z == 1) ? B1 : B2;
    unsigned short* Cm       = (blockIdx.z == 0) ? C0 : (blockIdx.z == 1) ? C1 : C2;

    __shared__ __align__(16) unsigned short As[2][128 * 32];  // 16 KB
    __shared__ __align__(16) unsigned short Bs[2][128 * 32];  // 16 KB

    const int t    = threadIdx.x;
    const int lane = t & 63;
    const int w    = t >> 6;
    const int m0   = blockIdx.y * 128;
    const int n0   = blockIdx.x * 128;
    const int wm   = (w & 1) * 64;
    const int wn   = (w >> 1) * 64;

    const int r0 = t >> 2;
    const int c0 = (t & 3) * 8;
    const unsigned short* Apa = A  + (size_t)(m0 + r0) * K + c0;
    const unsigned short* Apb = Apa + (size_t)64 * K;
    const unsigned short* Bpa = Bm + (size_t)(n0 + r0) * K + c0;
    const unsigned short* Bpb = Bpa + (size_t)64 * K;
    unsigned short* lA0 = &As[0][w * 512];
    unsigned short* lA1 = &As[0][2048 + w * 512];
    unsigned short* lB0 = &Bs[0][w * 512];
    unsigned short* lB1 = &Bs[0][2048 + w * 512];
    const int bufStr = 128 * 32;

    f32x4 acc[4][4];
#pragma unroll
    for (int i = 0; i < 4; ++i)
#pragma unroll
        for (int j = 0; j < 4; ++j) acc[i][j] = (f32x4){0.f, 0.f, 0.f, 0.f};

    const int fm = lane & 15;
    const int kg = lane >> 4;

    gl16(Apa, lA0);
    gl16(Apb, lA1);
    gl16(Bpa, lB0);
    gl16(Bpb, lB1);

    int cur = 0;
    for (int k0 = 0; k0 < K; k0 += 32) {
        __syncthreads();

        if (k0 + 32 < K) {
            const int nb = (cur ^ 1);
            gl16(Apa + k0 + 32, lA0 + nb * bufStr);
            gl16(Apb + k0 + 32, lA1 + nb * bufStr);
            gl16(Bpa + k0 + 32, lB0 + nb * bufStr);
            gl16(Bpb + k0 + 32, lB1 + nb * bufStr);
        }

        const unsigned short* Ab = &As[cur][0];
        const unsigned short* Bb = &Bs[cur][0];
        bf16x8 af[4], bfr[4];
#pragma unroll
        for (int im = 0; im < 4; ++im)
            af[im] = *(const bf16x8*)&Ab[(wm + im * 16 + fm) * 32 + kg * 8];
#pragma unroll
        for (int in = 0; in < 4; ++in)
            bfr[in] = *(const bf16x8*)&Bb[(wn + in * 16 + fm) * 32 + kg * 8];
#pragma unroll
        for (int im = 0; im < 4; ++im)
#pragma unroll
            for (int in = 0; in < 4; ++in)
                acc[im][in] = __builtin_amdgcn_mfma_f32_16x16x32_bf16(
                    af[im], bfr[in], acc[im][in], 0, 0, 0);

        cur ^= 1;
    }

#pragma unroll
    for (int im = 0; im < 4; ++im) {
#pragma unroll
        for (int in = 0; in < 4; ++in) {
            const int row = m0 + wm + im * 16 + kg * 4;
            const int col = n0 + wn + in * 16 + fm;
#pragma unroll
            for (int r = 0; r < 4; ++r)
                Cm[(size_t)(row + r) * N + col] = f2bf(acc[im][in][r]);
        }
    }
}

// -------------------------------------------------------- GEMM 64x128 ----
// O-projection (256 blocks keep the grid full where 128x128 would halve it).
__global__ __launch_bounds__(256) void gemm_bt_mfma(
    const unsigned short* __restrict__ A,
    const unsigned short* __restrict__ B0, const unsigned short* __restrict__ B1,
    const unsigned short* __restrict__ B2,
    void* __restrict__ C0, void* __restrict__ C1, void* __restrict__ C2,
    int M, int N, int K, int bf16out)
{
    const unsigned short* Bm = (blockIdx.z == 0) ? B0 : (blockIdx.z == 1) ? B1 : B2;
    void* Cm                 = (blockIdx.z == 0) ? C0 : (blockIdx.z == 1) ? C1 : C2;

    __shared__ __align__(16) unsigned short As[2][64 * 32];   //  8 KB
    __shared__ __align__(16) unsigned short Bs[2][128 * 32];  // 16 KB

    const int t    = threadIdx.x;
    const int lane = t & 63;
    const int w    = t >> 6;
    const int m0   = blockIdx.y * 64;
    const int n0   = blockIdx.x * 128;
    const int wm   = (w & 1) * 32;
    const int wn   = (w >> 1) * 64;

    const int r0 = t >> 2;
    const int c0 = (t & 3) * 8;
    const unsigned short* Apa = A  + (size_t)(m0 + r0) * K + c0;
    const unsigned short* Bpa = Bm + (size_t)(n0 + r0) * K + c0;
    const unsigned short* Bpb = Bm + (size_t)(n0 + r0 + 64) * K + c0;
    unsigned short* ldsA  = &As[0][w * 512];
    unsigned short* ldsB0 = &Bs[0][w * 512];
    unsigned short* ldsB1 = &Bs[0][2048 + w * 512];
    const int bufStrA = 64 * 32;
    const int bufStrB = 128 * 32;

    f32x4 acc[2][4];
#pragma unroll
    for (int i = 0; i < 2; ++i)
#pragma unroll
        for (int j = 0; j < 4; ++j) acc[i][j] = (f32x4){0.f, 0.f, 0.f, 0.f};

    const int fm = lane & 15;
    const int kg = lane >> 4;

    gl16(Apa, ldsA);
    gl16(Bpa, ldsB0);
    gl16(Bpb, ldsB1);

    int cur = 0;
    for (int k0 = 0; k0 < K; k0 += 32) {
        __syncthreads();

        if (k0 + 32 < K) {
            const int nb = (cur ^ 1);
            gl16(Apa + k0 + 32, ldsA  + nb * bufStrA);
            gl16(Bpa + k0 + 32, ldsB0 + nb * bufStrB);
            gl16(Bpb + k0 + 32, ldsB1 + nb * bufStrB);
        }

        const unsigned short* Ab = &As[cur][0];
        const unsigned short* Bb = &Bs[cur][0];
        bf16x8 af[2], bfr[4];
#pragma unroll
        for (int im = 0; im < 2; ++im)
            af[im] = *(const bf16x8*)&Ab[(wm + im * 16 + fm) * 32 + kg * 8];
#pragma unroll
        for (int in = 0; in < 4; ++in)
            bfr[in] = *(const bf16x8*)&Bb[(wn + in * 16 + fm) * 32 + kg * 8];
#pragma unroll
        for (int im = 0; im < 2; ++im)
#pragma unroll
            for (int in = 0; in < 4; ++in)
                acc[im][in] = __builtin_amdgcn_mfma_f32_16x16x32_bf16(
                    af[im], bfr[in], acc[im][in], 0, 0, 0);

        cur ^= 1;
    }

#pragma unroll
    for (int im = 0; im < 2; ++im) {
#pragma unroll
        for (int in = 0; in < 4; ++in) {
            const int row = m0 + wm + im * 16 + kg * 4;
            const int col = n0 + wn + in * 16 + fm;
            if (bf16out) {
                unsigned short* cp = (unsigned short*)Cm;
#pragma unroll
                for (int r = 0; r < 4; ++r)
                    cp[(size_t)(row + r) * N + col] = f2bf(acc[im][in][r]);
            } else {
                float* cp = (float*)Cm;
#pragma unroll
                for (int r = 0; r < 4; ++r)
                    cp[(size_t)(row + r) * N + col] = acc[im][in][r];
            }
        }
    }
}

// ----------------------------------------------------------- attention ----
// R11 keys-split: grid (8, 128); block = one (b,hd) x 128 q-rows, 4 waves.
// KV tile = 128 keys; wave wv owns keys [wv*32, wv*32+32) x ALL 128 q-rows.
// Eliminates the 4x cross-wave redundancy of K/V fragment reads:
//   per wave per tile: bk 2 b128 + ap 8 b128 + bv 1 b128 (vs 10 b128 per
//   64-key-equivalent before => LDS reads -45%). Q frags (aq[8]) and O
//   accumulators (oacc[8]) live in registers. Final 4-way cross-wave O/l
//   reduction through LDS overlaid on the dead K/P buffers.
// P-pack: v_cvt_pk_bf16_f32 (1 VALU op per pair).
#define KSTR  40    // K tile row stride (16 real d + 16 zero-pad + 8 pad)
#define VSTRD 136   // VsT row stride (128 keys + 8 pad)  => 17 quads, odd
#define PSTRD 136   // Ps row stride  (128 keys + 8 pad)  => 17 quads, odd

__global__ __launch_bounds__(256, 3) void attn_mfma(
    const unsigned short* __restrict__ Qb, const unsigned short* __restrict__ Kb,
    const unsigned short* __restrict__ Vb, unsigned short* __restrict__ Ob)
{
    // Ks [128][40] 10240 B | VsT [16][136] 4352 B | Ps [128][136] 34816 B
    // Red overlay: float[4][128][17] = 34816 B (after final barrier)
    __shared__ __align__(16) unsigned char smem[49408];
    unsigned short* Ks  = (unsigned short*)smem;
    unsigned short* VsT = (unsigned short*)(smem + 10240);
    unsigned short* Ps  = (unsigned short*)(smem + 14592);
    float*          Red = (float*)smem;

    const int t    = threadIdx.x;
    const int lane = t & 63;
    const int wv   = t >> 6;
    const int fm   = lane & 15;
    const int kg   = lane >> 4;
    const int bh   = blockIdx.y;
    const size_t base = ((size_t)(bh >> 6) << 20) + (size_t)(bh & 63) * 16;
    const int q0 = blockIdx.x * 128;
    const int wk = wv * 32;          // wave's key offset within tile

    // zero the K d-pad (cols 16..31) once; real cols rewritten per tile
    {
        const int row = t >> 1, seg = t & 1;
        *(uint4*)&Ks[row * KSTR + 16 + seg * 8] = make_uint4(0, 0, 0, 0);
    }

    // Q fragments (B-operand): row q0+m*16+fm, k=kg*8 (zero for kg>=2)
    union { uint4 u; bf16x8 h; } zz; zz.u = make_uint4(0, 0, 0, 0);
    bf16x8 aq[8];
#pragma unroll
    for (int m = 0; m < 8; ++m) {
        if (kg < 2)
            aq[m] = *(const bf16x8*)(Qb + base +
                     (size_t)(q0 + m * 16 + fm) * 1024 + kg * 8);
        else
            aq[m] = zz.h;
    }

    f32x4 oacc[8];
    float lp[8];
#pragma unroll
    for (int m = 0; m < 8; ++m) {
        oacc[m] = (f32x4){0.f, 0.f, 0.f, 0.f};
        lp[m] = 0.f;
    }

    for (int kt = 0; kt < 1024; kt += 128) {
        __syncthreads();
        // stage K (row-major, 16 real d) and V (transposed) — all 256 threads
        {
            const int row = t >> 1, seg = t & 1;
            *(uint4*)&Ks[row * KSTR + seg * 8] =
                *(const uint4*)(Kb + base + (size_t)(kt + row) * 1024 + seg * 8);
            uint4 v = *(const uint4*)(Vb + base + (size_t)(kt + row) * 1024 + seg * 8);
            const unsigned short* pv = (const unsigned short*)&v;
#pragma unroll
            for (int d = 0; d < 8; ++d)
                VsT[(seg * 8 + d) * VSTRD + row] = pv[d];
        }
        __syncthreads();

        // K fragments for THIS wave's 32 keys only
        const bf16x8 bk0 = *(const bf16x8*)&Ks[(wk + fm) * KSTR + kg * 8];
        const bf16x8 bk1 = *(const bf16x8*)&Ks[(wk + 16 + fm) * KSTR + kg * 8];

        // ---- transposed QK + exp2 + cvt_pk P-store (wave-local rows of Ps)
#pragma unroll
        for (int m = 0; m < 8; ++m) {
            f32x4 s0 = __builtin_amdgcn_mfma_f32_16x16x32_bf16(
                bk0, aq[m], (f32x4){0.f, 0.f, 0.f, 0.f}, 0, 0, 0);
            f32x4 s1 = __builtin_amdgcn_mfma_f32_16x16x32_bf16(
                bk1, aq[m], (f32x4){0.f, 0.f, 0.f, 0.f}, 0, 0, 0);
            const float p0 = __builtin_amdgcn_exp2f(s0[0]);
            const float p1 = __builtin_amdgcn_exp2f(s0[1]);
            const float p2 = __builtin_amdgcn_exp2f(s0[2]);
            const float p3 = __builtin_amdgcn_exp2f(s0[3]);
            const float p4 = __builtin_amdgcn_exp2f(s1[0]);
            const float p5 = __builtin_amdgcn_exp2f(s1[1]);
            const float p6 = __builtin_amdgcn_exp2f(s1[2]);
            const float p7 = __builtin_amdgcn_exp2f(s1[3]);
            lp[m] += ((p0 + p1) + (p2 + p3)) + ((p4 + p5) + (p6 + p7));
            unsigned short* prow = &Ps[(m * 16 + fm) * PSTRD + wk];
            *(uint2*)&prow[kg * 4]      = make_uint2(cvtpk(p0, p1), cvtpk(p2, p3));
            *(uint2*)&prow[16 + kg * 4] = make_uint2(cvtpk(p4, p5), cvtpk(p6, p7));
        }

        // ---- PV over this wave's 32 keys: one k=32 MFMA per q-group
        const bf16x8 bv = *(const bf16x8*)&VsT[fm * VSTRD + wk + kg * 8];
#pragma unroll
        for (int m = 0; m < 8; ++m) {
            const bf16x8 ap = *(const bf16x8*)&Ps[(m * 16 + fm) * PSTRD + wk + kg * 8];
            oacc[m] = __builtin_amdgcn_mfma_f32_16x16x32_bf16(ap, bv, oacc[m], 0, 0, 0);
        }
    }

    // l: sum the 4 kg-group partials -> every lane holds l_wave[q=m*16+fm]
#pragma unroll
    for (int m = 0; m < 8; ++m) {
        lp[m] += __shfl_xor(lp[m], 16, 64);
        lp[m] += __shfl_xor(lp[m], 32, 64);
    }

    __syncthreads();   // all waves done with Ks/VsT/Ps -> overlay Red
    // write per-wave partials: Red[wv][q][d], l at d=16
#pragma unroll
    for (int m = 0; m < 8; ++m) {
#pragma unroll
        for (int r = 0; r < 4; ++r)
            Red[((wv * 128) + m * 16 + kg * 4 + r) * 17 + fm] = oacc[m][r];
        if (kg == 0)
            Red[((wv * 128) + m * 16 + fm) * 17 + 16] = lp[m];
    }
    __syncthreads();

    // wave wv finalizes q-rows [wv*32, wv*32+32)
#pragma unroll
    for (int mp = 0; mp < 2; ++mp) {
#pragma unroll
        for (int r = 0; r < 4; ++r) {
            const int q = wv * 32 + mp * 16 + kg * 4 + r;
            const float o = Red[q * 17 + fm]         + Red[(128 + q) * 17 + fm] +
                            Red[(256 + q) * 17 + fm] + Red[(384 + q) * 17 + fm];
            const float l = Red[q * 17 + 16]         + Red[(128 + q) * 17 + 16] +
                            Red[(256 + q) * 17 + 16] + Red[(384 + q) * 17 + 16];
            Ob[base + (size_t)(q0 + q) * 1024 + fm] = f2bf(o / l);
        }
    }
}

// -------------------------------------------------------------- launch ----
extern "C" void kernel_launch(void* const* d_in, const int* in_sizes, int n_in,
                              void* d_out, int out_size, void* d_ws, size_t ws_size,
                              hipStream_t stream) {
    const float* x  = (const float*)d_in[0];
    const float* Wq = (const float*)d_in[1];
    const float* Wk = (const float*)d_in[2];
    const float* Wv = (const float*)d_in[3];
    const float* Wo = (const float*)d_in[4];
    float* out = (float*)d_out;

    const int M = 2048, N = 1024, Kd = 1024;
    const size_t MEG = 1048576;
    unsigned short* ws = (unsigned short*)d_ws;   // 28 MB high-water
    unsigned short* xb  = ws;
    unsigned short* Wqb = ws + 2 * MEG;
    unsigned short* Wkb = ws + 3 * MEG;
    unsigned short* Wvb = ws + 4 * MEG;
    unsigned short* Wob = ws + 5 * MEG;
    unsigned short* Qb  = ws + 6 * MEG;
    unsigned short* Kb  = ws + 8 * MEG;
    unsigned short* Vb  = ws + 10 * MEG;
    unsigned short* Ob  = ws + 12 * MEG;

    dim3 gc(1024, 6, 1);
    cast_to_bf16<<<gc, 256, 0, stream>>>(x, Wq, Wk, Wv, Wo, xb, Wqb, Wkb, Wvb, Wob);

    dim3 g1(N / 128, M / 128, 3);
    gemm128_bt_mfma<<<g1, 256, 0, stream>>>(xb, Wqb, Wkb, Wvb, Qb, Kb, Vb, M, N, Kd);

    dim3 g2(8, 128, 1);
    attn_mfma<<<g2, 256, 0, stream>>>(Qb, Kb, Vb, Ob);

    dim3 g3(N / 128, M / 64, 1);
    gemm_bt_mfma<<<g3, 256, 0, stream>>>(Ob, Wob, Wob, Wob, out, out, out, M, N, Kd, 0);
}